// Round 1
// baseline (2917.728 us; speedup 1.0000x reference)
//
#include <hip/hip_runtime.h>
#include <math.h>

// ---------------- problem constants ----------------
// b=1, t=16, ch_in=10, h=w=24, t_de=16, ch_de=12, K=5, N=25
// hw=576, M = 576*25 = 14400
// out: (1,16,3,24,24)=27648 floats, then loss scalar -> out_size 27649

// ---------------- workspace layout (float offsets) ----------------
#define OFF_PART 0            // 3,686,400 (max over conv partial buffers)
#define OFF_F1   3686400      // 589,824
#define OFF_F2   4276224      // 589,824
#define OFF_F3   4866048      // 589,824
#define OFF_WTT  5455872      // 3,686,400  WtT[p][6400]
#define OFF_DN   9142272      // 2,764,800  dnorm[p][n][td][cd]
#define OFF_OB   11907072     // 691,200    o[p][n][td][ch]
#define OFF_MN   12598272     // 4,032      mn[p][7]
#define OFF_MX   12602304     // 4,032
#define OFF_LP   12606336     // 576
// total 12,606,912 floats = 50.4 MB

// ---------------- min/max per pixel for the 7 normalization groups ----------------
// groups: g0: cd1-3 (joint), g1: cd4, g2: cd5-7 (joint), g3..g6: cd8..11 (per-channel)
__global__ __launch_bounds__(64) void minmax_kernel(const float* __restrict__ design,
                                                    float* __restrict__ mn_o,
                                                    float* __restrict__ mx_o) {
    int p = blockIdx.x;
    int py = p / 24, px = p % 24;
    int lane = threadIdx.x;
    float mn[7], mx[7];
#pragma unroll
    for (int g = 0; g < 7; g++) { mn[g] = 1e30f; mx[g] = -1e30f; }
    for (int e = lane; e < 400; e += 64) {
        int n = e / 16, td = e % 16;
        int yy = py + n / 5 - 2, xx = px + n % 5 - 2;
        bool ok = (yy >= 0 && yy < 24 && xx >= 0 && xx < 24);
#pragma unroll
        for (int cd = 1; cd < 12; cd++) {
            float v = ok ? design[(td * 12 + cd) * 576 + yy * 24 + xx] : 0.0f;
            int g = (cd <= 3) ? 0 : (cd == 4) ? 1 : (cd <= 7) ? 2 : 3 + (cd - 8);
            mn[g] = fminf(mn[g], v);
            mx[g] = fmaxf(mx[g], v);
        }
    }
#pragma unroll
    for (int s = 32; s >= 1; s >>= 1) {
#pragma unroll
        for (int g = 0; g < 7; g++) {
            mn[g] = fminf(mn[g], __shfl_xor(mn[g], s));
            mx[g] = fmaxf(mx[g], __shfl_xor(mx[g], s));
        }
    }
    if (lane == 0) {
#pragma unroll
        for (int g = 0; g < 7; g++) {
            mn_o[p * 7 + g] = mn[g];
            mx_o[p * 7 + g] = mx[g];
        }
    }
}

// ---------------- normalized d: dn[p][n][td][cd] ----------------
__global__ void dnorm_kernel(const float* __restrict__ design,
                             const float* __restrict__ mn,
                             const float* __restrict__ mx,
                             float* __restrict__ dn) {
    int idx = blockIdx.x * 256 + threadIdx.x;
    if (idx >= 14400 * 192) return;
    int cd = idx % 12;
    int td = (idx / 12) % 16;
    int n  = (idx / 192) % 25;
    int p  = idx / 4800;
    int py = p / 24, px = p % 24;
    int yy = py + n / 5 - 2, xx = px + n % 5 - 2;
    float v = (yy >= 0 && yy < 24 && xx >= 0 && xx < 24)
                  ? design[(td * 12 + cd) * 576 + yy * 24 + xx] : 0.0f;
    if (cd >= 1) {
        int g = (cd <= 3) ? 0 : (cd == 4) ? 1 : (cd <= 7) ? 2 : 3 + (cd - 8);
        float a = mn[p * 7 + g], b = mx[p * 7 + g];
        v = (v - a) / (b - a + 0.001f);
    }
    dn[idx] = v;
}

// ---------------- 3x3 conv, accumulate into partial buffer (no bias/act) ----------------
// grid: (cout/16, 4 row-bands of 6 rows, nsplit); block 192 threads.
// thread: ocg = tid&3 -> 4 ocs {4k+ocg}; pxg = tid>>2 -> row r=pxg>>3, x0=(pxg&7)*3 -> 3 px
// K processed in 16-channel chunks; cps chunks per split.
__global__ __launch_bounds__(192) void conv16_kernel(const float* __restrict__ in,
                                                     const float* __restrict__ wgt,
                                                     float* __restrict__ part,
                                                     int cin, int cps) {
    __shared__ float s_in[16 * 8 * 26];               // [cl][rr(8)][xx(26)]
    __shared__ __align__(16) float s_w[16 * 16 * 12]; // [cl][ocl(16)][q(12, pad)]
    int tid = threadIdx.x;
    int ocg = tid & 3;
    int pxg = tid >> 2;     // 0..47
    int r  = pxg >> 3;      // 0..5
    int x0 = (pxg & 7) * 3; // 0,3,..,21
    int band = blockIdx.y;
    int y0 = band * 6;
    int oc_base = blockIdx.x * 16;
    int cout = gridDim.x * 16;
    int chunk0 = blockIdx.z * cps;

    float acc[4][3];
#pragma unroll
    for (int k = 0; k < 4; k++)
#pragma unroll
        for (int pp = 0; pp < 3; pp++) acc[k][pp] = 0.0f;

    for (int cc = 0; cc < cps; cc++) {
        int cbase = (chunk0 + cc) * 16;
        __syncthreads();
        for (int e = tid; e < 3328; e += 192) {
            int cl = e / 208, rem = e % 208;
            int rr = rem / 26, xx = rem % 26;
            int y = y0 + rr - 1, x = xx - 1;
            float v = 0.0f;
            if (y >= 0 && y < 24 && x >= 0 && x < 24)
                v = in[(cbase + cl) * 576 + y * 24 + x];
            s_in[e] = v;
        }
        for (int e = tid; e < 2304; e += 192) {
            int ocl = e / 144, rem = e % 144;
            int cl = rem / 9, q = rem % 9;
            s_w[(cl * 16 + ocl) * 12 + q] = wgt[((long)(oc_base + ocl) * cin + cbase + cl) * 9 + q];
        }
        __syncthreads();
        for (int cl = 0; cl < 16; cl++) {
            float v[15];
#pragma unroll
            for (int dy = 0; dy < 3; dy++)
#pragma unroll
                for (int c5 = 0; c5 < 5; c5++)
                    v[dy * 5 + c5] = s_in[(cl * 8 + r + dy) * 26 + x0 + c5];
#pragma unroll
            for (int k = 0; k < 4; k++) {
                const float4* wp = (const float4*)&s_w[(cl * 16 + (k * 4 + ocg)) * 12];
                float4 w0 = wp[0], w1 = wp[1], w2 = wp[2];
#pragma unroll
                for (int pp = 0; pp < 3; pp++) {
                    float s = acc[k][pp];
                    s = fmaf(w0.x, v[0 * 5 + pp + 0], s);
                    s = fmaf(w0.y, v[0 * 5 + pp + 1], s);
                    s = fmaf(w0.z, v[0 * 5 + pp + 2], s);
                    s = fmaf(w0.w, v[1 * 5 + pp + 0], s);
                    s = fmaf(w1.x, v[1 * 5 + pp + 1], s);
                    s = fmaf(w1.y, v[1 * 5 + pp + 2], s);
                    s = fmaf(w1.z, v[2 * 5 + pp + 0], s);
                    s = fmaf(w1.w, v[2 * 5 + pp + 1], s);
                    s = fmaf(w2.x, v[2 * 5 + pp + 2], s);
                    acc[k][pp] = s;
                }
            }
        }
    }
    long zoff = (long)blockIdx.z * cout * 576;
#pragma unroll
    for (int k = 0; k < 4; k++)
#pragma unroll
        for (int pp = 0; pp < 3; pp++)
            part[zoff + (long)(oc_base + k * 4 + ocg) * 576 + (y0 + r) * 24 + x0 + pp] = acc[k][pp];
}

// ---------------- sum splits + bias + leaky ----------------
__global__ void act_leaky_kernel(const float* __restrict__ part,
                                 const float* __restrict__ bias,
                                 float* __restrict__ out, int total, int nsplit) {
    int idx = blockIdx.x * 256 + threadIdx.x;
    if (idx >= total) return;
    float s = 0.0f;
    for (int k = 0; k < nsplit; k++) s += part[(long)k * total + idx];
    s += bias[idx / 576];
    out[idx] = s >= 0.0f ? s : 0.01f * s;
}

// ---------------- tanh + transpose: part[6400][576] -> wtT[576][6400] ----------------
__global__ __launch_bounds__(256) void tanh_tr_kernel(const float* __restrict__ part,
                                                      const float* __restrict__ bias,
                                                      float* __restrict__ wtT) {
    __shared__ float tile[64][65];
    int oc0 = blockIdx.x * 64, p0 = blockIdx.y * 64;
    int tx = threadIdx.x, ty = threadIdx.y;
#pragma unroll
    for (int k = 0; k < 16; k++) {
        int row = ty + k * 4;
        tile[row][tx] = tanhf(part[(long)(oc0 + row) * 576 + p0 + tx] + bias[oc0 + row]);
    }
    __syncthreads();
#pragma unroll
    for (int k = 0; k < 16; k++) {
        int rr = ty + k * 4;
        wtT[(long)(p0 + rr) * 6400 + oc0 + tx] = tile[tx][rr];
    }
}

// ---------------- per-pixel stage: Wm, XTW, A, B, solve, o, loss partial ----------------
__global__ __launch_bounds__(256) void stagec_kernel(const float* __restrict__ dn,
                                                     const float* __restrict__ wtT,
                                                     const float* __restrict__ xin,
                                                     const float* __restrict__ gt,
                                                     float* __restrict__ ob,
                                                     float* __restrict__ lp) {
    int p = blockIdx.x;
    int py = p / 24, px = p % 24;
    int tid = threadIdx.x;
    __shared__ float sX[4800];    // [n][t][c]
    __shared__ float sW[6400];    // [n][i][j]
    __shared__ float sY[1200];    // [n][t][ch]
    __shared__ float sP[192];     // [c][j]
    __shared__ float sXTW[192];   // [c][u]
    __shared__ float sA[144];
    __shared__ float sB[36];
    __shared__ double dA[144];
    __shared__ double db[36];
    __shared__ float spara[36];   // [c][ch]
    __shared__ float sred[256];

    for (int e = tid; e < 4800; e += 256) sX[e] = dn[(long)p * 4800 + e];
    for (int e = tid; e < 6400; e += 256) sW[e] = wtT[(long)p * 6400 + e];
    for (int e = tid; e < 1200; e += 256) {
        int n = e / 48, t = (e % 48) / 3, ch = e % 3;
        int yy = py + n / 5 - 2, xx = px + n % 5 - 2;
        sY[e] = (yy >= 0 && yy < 24 && xx >= 0 && xx < 24)
                    ? xin[(t * 10 + ch) * 576 + yy * 24 + xx] : 0.0f;
    }
    if (tid < 144) sA[tid] = 0.0f;
    if (tid < 36) sB[tid] = 0.0f;
    __syncthreads();

    for (int n = 0; n < 25; n++) {
        const float* X = sX + n * 192;  // X[t*12+c]
        const float* W = sW + n * 256;  // W[t*16+j]
        if (tid < 192) {                // P = X^T W : P[c][j]
            int c = tid >> 4, j = tid & 15;
            float s = 0.0f;
#pragma unroll
            for (int t = 0; t < 16; t++) s = fmaf(X[t * 12 + c], W[t * 16 + j], s);
            sP[tid] = s;
        }
        __syncthreads();
        if (tid < 192) {                // XTW = P W^T + X^T : XTW[c][u]
            int c = tid >> 4, u = tid & 15;
            float s = X[u * 12 + c];
#pragma unroll
            for (int j = 0; j < 16; j++) s = fmaf(sP[c * 16 + j], W[u * 16 + j], s);
            sXTW[tid] = s;
        }
        __syncthreads();
        if (tid < 144) {                // A += XTW X
            int c = tid / 12, d2 = tid % 12;
            float s = 0.0f;
#pragma unroll
            for (int t = 0; t < 16; t++) s = fmaf(sXTW[c * 16 + t], X[t * 12 + d2], s);
            sA[tid] += s;
        } else if (tid < 180) {         // B += XTW Y (3 rhs)
            int e = tid - 144;
            int c = e / 3, ch = e % 3;
            float s = 0.0f;
#pragma unroll
            for (int t = 0; t < 16; t++) s = fmaf(sXTW[c * 16 + t], sY[n * 48 + t * 3 + ch], s);
            sB[e] += s;
        }
        __syncthreads();
    }

    if (tid < 144) dA[tid] = (double)sA[tid] + ((tid % 13 == 0) ? 0.01 : 0.0);
    if (tid < 36) db[tid] = (double)sB[tid];
    __syncthreads();

    if (tid == 0) {
        // Cholesky (lower) in LDS, double
        for (int kk = 0; kk < 12; kk++) {
            double d = dA[kk * 12 + kk];
            for (int q = 0; q < kk; q++) d -= dA[kk * 12 + q] * dA[kk * 12 + q];
            d = sqrt(d);
            dA[kk * 12 + kk] = d;
            double inv = 1.0 / d;
            for (int i = kk + 1; i < 12; i++) {
                double s = dA[i * 12 + kk];
                for (int q = 0; q < kk; q++) s -= dA[i * 12 + q] * dA[kk * 12 + q];
                dA[i * 12 + kk] = s * inv;
            }
        }
        for (int ch = 0; ch < 3; ch++) {
            double t2[12];
            for (int i = 0; i < 12; i++) {
                double s = db[i * 3 + ch];
                for (int q = 0; q < i; q++) s -= dA[i * 12 + q] * t2[q];
                t2[i] = s / dA[i * 12 + i];
            }
            for (int i = 11; i >= 0; i--) {
                double s = t2[i];
                for (int q = i + 1; q < 12; q++) s -= dA[q * 12 + i] * t2[q];
                t2[i] = s / dA[i * 12 + i];
            }
            for (int i = 0; i < 12; i++) spara[i * 3 + ch] = (float)t2[i];
        }
    }
    __syncthreads();

    // o = domain @ para, plus loss partial
    float lsum = 0.0f;
    for (int e = tid; e < 1200; e += 256) {
        int n = e / 48, td = (e % 48) / 3, ch = e % 3;
        float s = 0.0f;
#pragma unroll
        for (int c = 0; c < 12; c++) s = fmaf(sX[n * 192 + td * 12 + c], spara[c * 3 + ch], s);
        ob[((long)(p * 25 + n)) * 48 + td * 3 + ch] = s;
        int yy = py + n / 5 - 2, xx = px + n % 5 - 2;
        float rv = (yy >= 0 && yy < 24 && xx >= 0 && xx < 24)
                       ? gt[(td * 3 + ch) * 576 + yy * 24 + xx] : 0.0f;
        lsum += fabsf(s - rv);
    }
    sred[tid] = lsum;
    __syncthreads();
    for (int s = 128; s >= 1; s >>= 1) {
        if (tid < s) sred[tid] += sred[tid + s];
        __syncthreads();
    }
    if (tid == 0) lp[p] = sred[0];
}

// ---------------- fold (overlap-add) + normalize ----------------
__global__ void fold_kernel(const float* __restrict__ ob, float* __restrict__ out) {
    int idx = blockIdx.x * 256 + threadIdx.x;
    if (idx >= 27648) return;
    int td = idx / 1728;
    int rem = idx % 1728;
    int ch = rem / 576;
    int p = rem % 576;
    int y = p / 24, x = p % 24;
    float num = 0.0f;
    int den = 0;
    for (int i = 0; i < 5; i++) {
        int yy = y + 2 - i;
        if (yy < 0 || yy >= 24) continue;
        for (int j = 0; j < 5; j++) {
            int xx = x + 2 - j;
            if (xx < 0 || xx >= 24) continue;
            num += ob[((long)((yy * 24 + xx) * 25 + i * 5 + j)) * 48 + td * 3 + ch];
            den++;
        }
    }
    out[idx] = num / (float)den;
}

// ---------------- final loss reduce ----------------
__global__ __launch_bounds__(64) void loss_kernel(const float* __restrict__ lp,
                                                  float* __restrict__ out) {
    int t = threadIdx.x;
    float s = 0.0f;
    for (int e = t; e < 576; e += 64) s += lp[e];
#pragma unroll
    for (int d = 32; d >= 1; d >>= 1) s += __shfl_xor(s, d);
    if (t == 0) out[27648] = s / 691200.0f;
}

// ---------------- launch ----------------
extern "C" void kernel_launch(void* const* d_in, const int* in_sizes, int n_in,
                              void* d_out, int out_size, void* d_ws, size_t ws_size,
                              hipStream_t stream) {
    const float* x      = (const float*)d_in[0];
    const float* design = (const float*)d_in[1];
    const float* gt     = (const float*)d_in[2];
    const float* w1     = (const float*)d_in[3];
    const float* b1     = (const float*)d_in[4];
    const float* w2     = (const float*)d_in[5];
    const float* b2     = (const float*)d_in[6];
    const float* w3     = (const float*)d_in[7];
    const float* b3     = (const float*)d_in[8];
    const float* wf     = (const float*)d_in[9];
    const float* bf     = (const float*)d_in[10];
    float* out = (float*)d_out;
    float* ws  = (float*)d_ws;

    float* part = ws + OFF_PART;
    float* f1   = ws + OFF_F1;
    float* f2   = ws + OFF_F2;
    float* f3   = ws + OFF_F3;
    float* wtT  = ws + OFF_WTT;
    float* dn   = ws + OFF_DN;
    float* ob   = ws + OFF_OB;
    float* mn   = ws + OFF_MN;
    float* mx   = ws + OFF_MX;
    float* lp   = ws + OFF_LP;

    minmax_kernel<<<576, 64, 0, stream>>>(design, mn, mx);
    dnorm_kernel<<<10800, 256, 0, stream>>>(design, mn, mx, dn);

    // conv1: cin=160 (10 chunks), 5 splits x 2 chunks
    conv16_kernel<<<dim3(64, 4, 5), 192, 0, stream>>>(x, w1, part, 160, 2);
    act_leaky_kernel<<<2304, 256, 0, stream>>>(part, b1, f1, 589824, 5);
    // conv2: cin=1024 (64 chunks), 4 splits x 16 chunks
    conv16_kernel<<<dim3(64, 4, 4), 192, 0, stream>>>(f1, w2, part, 1024, 16);
    act_leaky_kernel<<<2304, 256, 0, stream>>>(part, b2, f2, 589824, 4);
    // conv3
    conv16_kernel<<<dim3(64, 4, 4), 192, 0, stream>>>(f2, w3, part, 1024, 16);
    act_leaky_kernel<<<2304, 256, 0, stream>>>(part, b3, f3, 589824, 4);
    // convf: cout=6400, 1 split x 64 chunks
    conv16_kernel<<<dim3(400, 4, 1), 192, 0, stream>>>(f3, wf, part, 1024, 64);
    tanh_tr_kernel<<<dim3(100, 9), dim3(64, 4), 0, stream>>>(part, bf, wtT);

    stagec_kernel<<<576, 256, 0, stream>>>(dn, wtT, x, gt, ob, lp);
    fold_kernel<<<108, 256, 0, stream>>>(ob, out);
    loss_kernel<<<1, 64, 0, stream>>>(lp, out);
}

// Round 2
// 1326.434 us; speedup vs baseline: 2.1997x; 2.1997x over previous
//
#include <hip/hip_runtime.h>
#include <math.h>

// ---------------- problem constants ----------------
// b=1, t=16, ch_in=10, h=w=24, t_de=16, ch_de=12, K=5, N=25
// hw=576, M = 576*25 = 14400; out: 27648 + loss = 27649 floats

typedef __attribute__((ext_vector_type(8))) short sh8;
typedef __attribute__((ext_vector_type(4))) float f32x4;

// ---------------- workspace layout (byte offsets) ----------------
#define OFF_PART 0UL                   // 58,982,400 (max: convf 4 splits x 6400x576x4)
#define OFF_ACTX 58982400UL            // 5 chunks x 2 x 55296
#define OFF_AF1  59535360UL            // 32 x 2 x 55296
#define OFF_AF2  63074304UL
#define OFF_AF3  66613248UL
#define OFF_WTT  70152192UL            // 6400x576 fp32
#define OFF_DN   84897792UL            // 14400x192 fp32
#define OFF_OB   95956992UL            // 14400x48 fp32
#define OFF_MN   98721792UL            // 576x7 fp32
#define OFF_MX   98737920UL
#define OFF_LP   98754048UL            // 576 fp32
// total ~94.2 MB

#define CHUNK_BYTES 55296              // 688 rows x 80B + round to 54*1024

// ---------------- bf16 helpers ----------------
__device__ inline unsigned short bf16_rne(float f) {
    unsigned int u = __builtin_bit_cast(unsigned int, f);
    unsigned int r = (u + 0x7FFFu + ((u >> 16) & 1u)) >> 16;
    return (unsigned short)r;
}
__device__ inline void bf16_split(float v, unsigned short& h, unsigned short& l) {
    h = bf16_rne(v);
    float fh = __builtin_bit_cast(float, ((unsigned int)h) << 16);
    l = bf16_rne(v - fh);
}
__device__ inline void glds16(const void* gsrc, void* ldst) {
    __builtin_amdgcn_global_load_lds((const __attribute__((address_space(1))) void*)gsrc,
                                     (__attribute__((address_space(3))) void*)ldst, 16, 0, 0);
}

// ---------------- min/max per pixel for the 7 normalization groups ----------------
__global__ __launch_bounds__(64) void minmax_kernel(const float* __restrict__ design,
                                                    float* __restrict__ mn_o,
                                                    float* __restrict__ mx_o) {
    int p = blockIdx.x;
    int py = p / 24, px = p % 24;
    int lane = threadIdx.x;
    float mn[7], mx[7];
#pragma unroll
    for (int g = 0; g < 7; g++) { mn[g] = 1e30f; mx[g] = -1e30f; }
    for (int e = lane; e < 400; e += 64) {
        int n = e / 16, td = e % 16;
        int yy = py + n / 5 - 2, xx = px + n % 5 - 2;
        bool ok = (yy >= 0 && yy < 24 && xx >= 0 && xx < 24);
#pragma unroll
        for (int cd = 1; cd < 12; cd++) {
            float v = ok ? design[(td * 12 + cd) * 576 + yy * 24 + xx] : 0.0f;
            int g = (cd <= 3) ? 0 : (cd == 4) ? 1 : (cd <= 7) ? 2 : 3 + (cd - 8);
            mn[g] = fminf(mn[g], v);
            mx[g] = fmaxf(mx[g], v);
        }
    }
#pragma unroll
    for (int s = 32; s >= 1; s >>= 1) {
#pragma unroll
        for (int g = 0; g < 7; g++) {
            mn[g] = fminf(mn[g], __shfl_xor(mn[g], s));
            mx[g] = fmaxf(mx[g], __shfl_xor(mx[g], s));
        }
    }
    if (lane == 0) {
#pragma unroll
        for (int g = 0; g < 7; g++) {
            mn_o[p * 7 + g] = mn[g];
            mx_o[p * 7 + g] = mx[g];
        }
    }
}

// ---------------- normalized d: dn[p][n][td][cd] ----------------
__global__ void dnorm_kernel(const float* __restrict__ design,
                             const float* __restrict__ mn,
                             const float* __restrict__ mx,
                             float* __restrict__ dn) {
    int idx = blockIdx.x * 256 + threadIdx.x;
    if (idx >= 14400 * 192) return;
    int cd = idx % 12;
    int td = (idx / 12) % 16;
    int n  = (idx / 192) % 25;
    int p  = idx / 4800;
    int py = p / 24, px = p % 24;
    int yy = py + n / 5 - 2, xx = px + n % 5 - 2;
    float v = (yy >= 0 && yy < 24 && xx >= 0 && xx < 24)
                  ? design[(td * 12 + cd) * 576 + yy * 24 + xx] : 0.0f;
    if (cd >= 1) {
        int g = (cd <= 3) ? 0 : (cd == 4) ? 1 : (cd <= 7) ? 2 : 3 + (cd - 8);
        float a = mn[p * 7 + g], b = mx[p * 7 + g];
        v = (v - a) / (b - a + 0.001f);
    }
    dn[idx] = v;
}

// ---------------- activation -> padded bf16 hi/lo chunk layout ----------------
// actH chunk layout per c32: [2(hi,lo)][688 pos][40 halves] ; chunk stride 2*55296 B
// pos = yp*26+xp over padded 26x26; border/pad entries zero.
__global__ __launch_bounds__(256) void fact_kernel(const float* __restrict__ src,  // [nsplit][cout][576] or raw
                                                   const float* __restrict__ bias, // may be null
                                                   char* __restrict__ actH,
                                                   int cout, int nsplit, int do_act) {
    __shared__ float tile[32 * 577];
    int c32 = blockIdx.x;
    int tid = threadIdx.x;
    for (int e = tid; e < 32 * 576; e += 256) {
        int ocl = e / 576, p = e % 576;
        long base = ((long)(c32 * 32 + ocl)) * 576 + p;
        float s = 0.f;
        for (int k = 0; k < nsplit; ++k) s += src[base + (long)k * cout * 576];
        tile[ocl * 577 + p] = s;
    }
    __syncthreads();
    char* outp = actH + (long)c32 * 2 * CHUNK_BYTES;
    for (int e = tid; e < 688 * 40; e += 256) {
        int pos = e / 40, j = e % 40;
        unsigned short h = 0, l = 0;
        if (pos < 676 && j < 32) {
            int y = pos / 26, x = pos % 26;
            if (y >= 1 && y <= 24 && x >= 1 && x <= 24) {
                float v = tile[j * 577 + (y - 1) * 24 + (x - 1)];
                if (do_act) { v += bias[c32 * 32 + j]; v = v >= 0.f ? v : 0.01f * v; }
                bf16_split(v, h, l);
            }
        }
        *(unsigned short*)(outp + (long)pos * 80 + j * 2) = h;
        *(unsigned short*)(outp + CHUNK_BYTES + (long)pos * 80 + j * 2) = l;
    }
}

// ---------------- MFMA implicit-GEMM 3x3 conv ----------------
// Block: 64 oc x 576 px (whole image), 4 waves; wave w: rows [w*6, w*6+6) = 144 px.
// K-chunk = (tap, 32 ic). Weights read fp32 on the fly, split to bf16 hi/lo, ds_write staged (dbuf).
// Activations staged via global_load_lds from pre-padded actH chunks (hi & lo).
// 3 products per k-chunk: Wh*Xh + Wl*Xh + Wh*Xl.
template<int CPS>
__global__ __launch_bounds__(256, 1)
void conv_mfma_kernel(const char* __restrict__ actH,   // [ncc][2][55296B]
                      const float* __restrict__ wgt,   // [cout][cin][9] fp32
                      float* __restrict__ part,        // [ksplit][cout][576]
                      int cin, int cout) {
    __shared__ __align__(1024) char sB[2 * CHUNK_BYTES];   // hi @0, lo @55296
    __shared__ __align__(1024) short sW[2][2][64][40];     // [buf][h/l][oc][k+pad]

    const int tid = threadIdx.x;
    const int lane = tid & 63;
    const int w = tid >> 6;
    const int q = lane >> 4;
    const int ln15 = lane & 15;
    const int ocb = blockIdx.x;
    const int s = blockIdx.y;

    int baddr[9];
#pragma unroll
    for (int j = 0; j < 9; ++j) {
        int pix = w * 144 + j * 16 + ln15;
        int y = pix / 24, x = pix % 24;
        baddr[j] = (y * 26 + x) * 80 + q * 16;
    }
    const int oc_l = tid >> 2;   // 0..63
    const int g = tid & 3;       // ic subgroup (8 each)
    const long wbase = (long)(ocb * 64 + oc_l) * cin * 9;

    f32x4 acc[4][9];
#pragma unroll
    for (int a = 0; a < 4; ++a)
#pragma unroll
        for (int j = 0; j < 9; ++j) acc[a][j] = f32x4{0.f, 0.f, 0.f, 0.f};

#pragma unroll 1
    for (int cc = 0; cc < CPS; ++cc) {
        const int c32 = s * CPS + cc;
        __syncthreads();   // full drain: prev chunk compute done, safe to overwrite sB
        {
            const char* hsrc = actH + (long)(c32 * 2 + 0) * CHUNK_BYTES;
            const char* lsrc = actH + (long)(c32 * 2 + 1) * CHUNK_BYTES;
            for (int i = w; i < 54; i += 4) {
                glds16(hsrc + i * 1024 + lane * 16, sB + i * 1024);
                glds16(lsrc + i * 1024 + lane * 16, sB + CHUNK_BYTES + i * 1024);
            }
        }
        const float* wp2 = wgt + wbase + (long)(c32 * 32 + g * 8) * 9;
        float wv[8];
#pragma unroll
        for (int e = 0; e < 8; ++e) wv[e] = wp2[e * 9 + 0];

#pragma unroll
        for (int tap = 0; tap < 9; ++tap) {
            // convert current tap's weights, stage to LDS (waits wv via vmcnt; covers GLDS at tap 0)
            sh8 h8, l8;
#pragma unroll
            for (int e = 0; e < 8; ++e) {
                unsigned short h, l;
                bf16_split(wv[e], h, l);
                h8[e] = (short)h; l8[e] = (short)l;
            }
            *(sh8*)&sW[tap & 1][0][oc_l][g * 8] = h8;
            *(sh8*)&sW[tap & 1][1][oc_l][g * 8] = l8;
            // prefetch next tap's weights (stays outstanding across the raw barrier)
            float wn[8];
            if (tap < 8) {
#pragma unroll
                for (int e = 0; e < 8; ++e) wn[e] = wp2[e * 9 + tap + 1];
            }
            asm volatile("s_waitcnt lgkmcnt(0)" ::: "memory");
            __builtin_amdgcn_s_barrier();
            __builtin_amdgcn_sched_barrier(0);
            // compute this k-chunk
            const int dby = ((tap / 3) * 26 + (tap % 3)) * 80;
            sh8 bh[9], bl[9];
#pragma unroll
            for (int j = 0; j < 9; ++j) {
                bh[j] = *(const sh8*)(sB + baddr[j] + dby);
                bl[j] = *(const sh8*)(sB + CHUNK_BYTES + baddr[j] + dby);
            }
#pragma unroll
            for (int ot = 0; ot < 4; ++ot) {
                sh8 ah = *(const sh8*)&sW[tap & 1][0][ot * 16 + ln15][q * 8];
                sh8 al = *(const sh8*)&sW[tap & 1][1][ot * 16 + ln15][q * 8];
#pragma unroll
                for (int j = 0; j < 9; ++j) {
                    acc[ot][j] = __builtin_amdgcn_mfma_f32_16x16x32_bf16(ah, bh[j], acc[ot][j], 0, 0, 0);
                    acc[ot][j] = __builtin_amdgcn_mfma_f32_16x16x32_bf16(al, bh[j], acc[ot][j], 0, 0, 0);
                    acc[ot][j] = __builtin_amdgcn_mfma_f32_16x16x32_bf16(ah, bl[j], acc[ot][j], 0, 0, 0);
                }
            }
#pragma unroll
            for (int e = 0; e < 8; ++e) wv[e] = wn[e];
        }
    }
    // epilogue: D[row=oc via (lane>>4)*4+r][col=px via lane&15]
#pragma unroll
    for (int ot = 0; ot < 4; ++ot)
#pragma unroll
        for (int j = 0; j < 9; ++j) {
            int px = w * 144 + j * 16 + ln15;
#pragma unroll
            for (int r = 0; r < 4; ++r) {
                int oc = ocb * 64 + ot * 16 + q * 4 + r;
                part[((long)s * cout + oc) * 576 + px] = acc[ot][j][r];
            }
        }
}

// ---------------- tanh + sum 4 splits + transpose: part -> wtT[576][6400] ----------------
__global__ __launch_bounds__(256) void tanh_tr_kernel(const float* __restrict__ part,
                                                      const float* __restrict__ bias,
                                                      float* __restrict__ wtT) {
    __shared__ float tile[64][65];
    int oc0 = blockIdx.x * 64, p0 = blockIdx.y * 64;
    int tx = threadIdx.x, ty = threadIdx.y;
#pragma unroll
    for (int k = 0; k < 16; k++) {
        int row = ty + k * 4;
        float s = 0.f;
#pragma unroll
        for (int sp = 0; sp < 4; ++sp)
            s += part[((long)sp * 6400 + oc0 + row) * 576 + p0 + tx];
        tile[row][tx] = tanhf(s + bias[oc0 + row]);
    }
    __syncthreads();
#pragma unroll
    for (int k = 0; k < 16; k++) {
        int rr = ty + k * 4;
        wtT[(long)(p0 + rr) * 6400 + oc0 + tx] = tile[tx][rr];
    }
}

// ---------------- per-pixel stage: Wm, XTW, A, B, solve, o, loss partial ----------------
__global__ __launch_bounds__(256) void stagec_kernel(const float* __restrict__ dn,
                                                     const float* __restrict__ wtT,
                                                     const float* __restrict__ xin,
                                                     const float* __restrict__ gt,
                                                     float* __restrict__ ob,
                                                     float* __restrict__ lp) {
    int p = blockIdx.x;
    int py = p / 24, px = p % 24;
    int tid = threadIdx.x;
    __shared__ float sX[4800];
    __shared__ float sW[6400];
    __shared__ float sY[1200];
    __shared__ float sP[192];
    __shared__ float sXTW[192];
    __shared__ float sA[144];
    __shared__ float sB[36];
    __shared__ double dA[144];
    __shared__ double db[36];
    __shared__ float spara[36];
    __shared__ float sred[256];

    for (int e = tid; e < 4800; e += 256) sX[e] = dn[(long)p * 4800 + e];
    for (int e = tid; e < 6400; e += 256) sW[e] = wtT[(long)p * 6400 + e];
    for (int e = tid; e < 1200; e += 256) {
        int n = e / 48, t = (e % 48) / 3, ch = e % 3;
        int yy = py + n / 5 - 2, xx = px + n % 5 - 2;
        sY[e] = (yy >= 0 && yy < 24 && xx >= 0 && xx < 24)
                    ? xin[(t * 10 + ch) * 576 + yy * 24 + xx] : 0.0f;
    }
    if (tid < 144) sA[tid] = 0.0f;
    if (tid < 36) sB[tid] = 0.0f;
    __syncthreads();

    for (int n = 0; n < 25; n++) {
        const float* X = sX + n * 192;
        const float* W = sW + n * 256;
        if (tid < 192) {
            int c = tid >> 4, j = tid & 15;
            float s = 0.0f;
#pragma unroll
            for (int t = 0; t < 16; t++) s = fmaf(X[t * 12 + c], W[t * 16 + j], s);
            sP[tid] = s;
        }
        __syncthreads();
        if (tid < 192) {
            int c = tid >> 4, u = tid & 15;
            float s = X[u * 12 + c];
#pragma unroll
            for (int j = 0; j < 16; j++) s = fmaf(sP[c * 16 + j], W[u * 16 + j], s);
            sXTW[tid] = s;
        }
        __syncthreads();
        if (tid < 144) {
            int c = tid / 12, d2 = tid % 12;
            float s = 0.0f;
#pragma unroll
            for (int t = 0; t < 16; t++) s = fmaf(sXTW[c * 16 + t], X[t * 12 + d2], s);
            sA[tid] += s;
        } else if (tid < 180) {
            int e = tid - 144;
            int c = e / 3, ch = e % 3;
            float s = 0.0f;
#pragma unroll
            for (int t = 0; t < 16; t++) s = fmaf(sXTW[c * 16 + t], sY[n * 48 + t * 3 + ch], s);
            sB[e] += s;
        }
        __syncthreads();
    }

    if (tid < 144) dA[tid] = (double)sA[tid] + ((tid % 13 == 0) ? 0.01 : 0.0);
    if (tid < 36) db[tid] = (double)sB[tid];
    __syncthreads();

    if (tid == 0) {
        for (int kk = 0; kk < 12; kk++) {
            double d = dA[kk * 12 + kk];
            for (int q2 = 0; q2 < kk; q2++) d -= dA[kk * 12 + q2] * dA[kk * 12 + q2];
            d = sqrt(d);
            dA[kk * 12 + kk] = d;
            double inv = 1.0 / d;
            for (int i = kk + 1; i < 12; i++) {
                double s = dA[i * 12 + kk];
                for (int q2 = 0; q2 < kk; q2++) s -= dA[i * 12 + q2] * dA[kk * 12 + q2];
                dA[i * 12 + kk] = s * inv;
            }
        }
        for (int ch = 0; ch < 3; ch++) {
            double t2[12];
            for (int i = 0; i < 12; i++) {
                double s = db[i * 3 + ch];
                for (int q2 = 0; q2 < i; q2++) s -= dA[i * 12 + q2] * t2[q2];
                t2[i] = s / dA[i * 12 + i];
            }
            for (int i = 11; i >= 0; i--) {
                double s = t2[i];
                for (int q2 = i + 1; q2 < 12; q2++) s -= dA[q2 * 12 + i] * t2[q2];
                t2[i] = s / dA[i * 12 + i];
            }
            for (int i = 0; i < 12; i++) spara[i * 3 + ch] = (float)t2[i];
        }
    }
    __syncthreads();

    float lsum = 0.0f;
    for (int e = tid; e < 1200; e += 256) {
        int n = e / 48, td = (e % 48) / 3, ch = e % 3;
        float s = 0.0f;
#pragma unroll
        for (int c = 0; c < 12; c++) s = fmaf(sX[n * 192 + td * 12 + c], spara[c * 3 + ch], s);
        ob[((long)(p * 25 + n)) * 48 + td * 3 + ch] = s;
        int yy = py + n / 5 - 2, xx = px + n % 5 - 2;
        float rv = (yy >= 0 && yy < 24 && xx >= 0 && xx < 24)
                       ? gt[(td * 3 + ch) * 576 + yy * 24 + xx] : 0.0f;
        lsum += fabsf(s - rv);
    }
    sred[tid] = lsum;
    __syncthreads();
    for (int s = 128; s >= 1; s >>= 1) {
        if (tid < s) sred[tid] += sred[tid + s];
        __syncthreads();
    }
    if (tid == 0) lp[p] = sred[0];
}

// ---------------- fold (overlap-add) + normalize ----------------
__global__ void fold_kernel(const float* __restrict__ ob, float* __restrict__ out) {
    int idx = blockIdx.x * 256 + threadIdx.x;
    if (idx >= 27648) return;
    int td = idx / 1728;
    int rem = idx % 1728;
    int ch = rem / 576;
    int p = rem % 576;
    int y = p / 24, x = p % 24;
    float num = 0.0f;
    int den = 0;
    for (int i = 0; i < 5; i++) {
        int yy = y + 2 - i;
        if (yy < 0 || yy >= 24) continue;
        for (int j = 0; j < 5; j++) {
            int xx = x + 2 - j;
            if (xx < 0 || xx >= 24) continue;
            num += ob[((long)((yy * 24 + xx) * 25 + i * 5 + j)) * 48 + td * 3 + ch];
            den++;
        }
    }
    out[idx] = num / (float)den;
}

// ---------------- final loss reduce ----------------
__global__ __launch_bounds__(64) void loss_kernel(const float* __restrict__ lp,
                                                  float* __restrict__ out) {
    int t = threadIdx.x;
    float s = 0.0f;
    for (int e = t; e < 576; e += 64) s += lp[e];
#pragma unroll
    for (int d = 32; d >= 1; d >>= 1) s += __shfl_xor(s, d);
    if (t == 0) out[27648] = s / 691200.0f;
}

// ---------------- launch ----------------
extern "C" void kernel_launch(void* const* d_in, const int* in_sizes, int n_in,
                              void* d_out, int out_size, void* d_ws, size_t ws_size,
                              hipStream_t stream) {
    const float* x      = (const float*)d_in[0];
    const float* design = (const float*)d_in[1];
    const float* gt     = (const float*)d_in[2];
    const float* w1     = (const float*)d_in[3];
    const float* b1     = (const float*)d_in[4];
    const float* w2     = (const float*)d_in[5];
    const float* b2     = (const float*)d_in[6];
    const float* w3     = (const float*)d_in[7];
    const float* b3     = (const float*)d_in[8];
    const float* wf     = (const float*)d_in[9];
    const float* bf     = (const float*)d_in[10];
    float* out = (float*)d_out;
    char* wsb  = (char*)d_ws;

    float* part = (float*)(wsb + OFF_PART);
    char*  actX = wsb + OFF_ACTX;
    char*  aF1  = wsb + OFF_AF1;
    char*  aF2  = wsb + OFF_AF2;
    char*  aF3  = wsb + OFF_AF3;
    float* wtT  = (float*)(wsb + OFF_WTT);
    float* dn   = (float*)(wsb + OFF_DN);
    float* ob   = (float*)(wsb + OFF_OB);
    float* mn   = (float*)(wsb + OFF_MN);
    float* mx   = (float*)(wsb + OFF_MX);
    float* lp   = (float*)(wsb + OFF_LP);

    minmax_kernel<<<576, 64, 0, stream>>>(design, mn, mx);
    dnorm_kernel<<<10800, 256, 0, stream>>>(design, mn, mx, dn);

    // x -> bf16 hi/lo padded chunks (160 ch = 5 chunks)
    fact_kernel<<<5, 256, 0, stream>>>(x, nullptr, actX, 160, 1, 0);
    // conv1: cin=160 (5 chunks), ksplit=5, CPS=1
    conv_mfma_kernel<1><<<dim3(16, 5), 256, 0, stream>>>(actX, w1, part, 160, 1024);
    fact_kernel<<<32, 256, 0, stream>>>(part, b1, aF1, 1024, 5, 1);
    // conv2: cin=1024 (32 chunks), ksplit=16, CPS=2
    conv_mfma_kernel<2><<<dim3(16, 16), 256, 0, stream>>>(aF1, w2, part, 1024, 1024);
    fact_kernel<<<32, 256, 0, stream>>>(part, b2, aF2, 1024, 16, 1);
    // conv3
    conv_mfma_kernel<2><<<dim3(16, 16), 256, 0, stream>>>(aF2, w3, part, 1024, 1024);
    fact_kernel<<<32, 256, 0, stream>>>(part, b3, aF3, 1024, 16, 1);
    // convf: cout=6400, ksplit=4, CPS=8
    conv_mfma_kernel<8><<<dim3(100, 4), 256, 0, stream>>>(aF3, wf, part, 1024, 6400);
    tanh_tr_kernel<<<dim3(100, 9), dim3(64, 4), 0, stream>>>(part, bf, wtT);

    stagec_kernel<<<576, 256, 0, stream>>>(dn, wtT, x, gt, ob, lp);
    fold_kernel<<<108, 256, 0, stream>>>(ob, out);
    loss_kernel<<<1, 64, 0, stream>>>(lp, out);
}